// Round 8
// baseline (214.647 us; speedup 1.0000x reference)
//
#include <hip/hip_runtime.h>

// Fully fused pipeline (h, f, pf never touch HBM):
//   k_fused: block (b, s=0..1) covers f-rows 14s..14s+13:
//     P1 conv1+relu+pool -> LDS h-tile[8][30][60] (h-rows 28s-1..28s+28, zero halo)
//     P2 conv2+relu+pool: wave q owns oc 4q..4q+3 (SGPR weights); lanes sweep
//        392 f-pixels fx-major (stride-2 LDS = conflict-free); patch-linear
//        contributions accumulated into bias-seeded pfp[392] via LDS atomicAdd
//     P3 fc1 partial: h1p[b][s][64] = w_fc1[:, 392s..392s+391] . pfp
//   k_tail: h1 = relu(sum_s h1p + b_fc1); fc2; log_softmax -> out[512,10]
// All fp32.

#define HSTR 60   // 58 used cols (56 + 2 halo) + 2 pad (even -> aligned float2)
#define NROWS 30  // 28 tile h-rows + 2 halo

#define C9(J, K)                                                             \
  (win[J][K] * w0_ + win[J][K + 1] * w1_ + win[J][K + 2] * w2_ +             \
   win[J + 1][K] * w3_ + win[J + 1][K + 1] * w4_ + win[J + 1][K + 2] * w5_ + \
   win[J + 2][K] * w6_ + win[J + 2][K + 1] * w7_ + win[J + 2][K + 2] * w8_)

__global__ __launch_bounds__(256) void k_fused(
    const float* __restrict__ x, const float* __restrict__ w1,
    const float* __restrict__ b1, const float* __restrict__ w2,
    const float* __restrict__ b2, const float* __restrict__ wp,
    const float* __restrict__ bp, const float* __restrict__ w_fc1,
    float* __restrict__ h1p) {
  __shared__ __align__(16) float hs[8 * NROWS * HSTR];  // 14400 f = 57.6 KB
  __shared__ __align__(16) float pfp[392];              // patch accum, bias-seeded
  const int tid = threadIdx.x;
  const int b = blockIdx.x >> 1;
  const int s = blockIdx.x & 1;

  for (int i = tid; i < 8 * NROWS * HSTR; i += 256) hs[i] = 0.f;
  for (int t = tid; t < 392; t += 256) pfp[t] = bp[t & 3];
  __syncthreads();

  // ---- Phase 1: conv1(1->8)+bias+relu+maxpool2 into LDS tile ----
  // tile row r 0..29 <-> global pooled-h row gr = 28s-1+r; halo rows/cols = 0.
  // h col hc stored at col 1+hc (col 0 / 57 = zero halo).
  const float* xb = x + (long)b * 12544;  // x[b], 112x112
  for (int task = tid; task < 1680; task += 256) {
    int r = task / 56, hc = task % 56;
    int gr = 28 * s - 1 + r;
    if ((unsigned)gr >= 56u) continue;
    float win[4][4];
    int iy0 = 2 * gr - 1, ix0 = 2 * hc - 1;
#pragma unroll
    for (int rr = 0; rr < 4; ++rr) {
      int iy = iy0 + rr;
      bool yok = (unsigned)iy < 112u;
#pragma unroll
      for (int qq = 0; qq < 4; ++qq) {
        int ix = ix0 + qq;
        win[rr][qq] = (yok && (unsigned)ix < 112u) ? xb[iy * 112 + ix] : 0.f;
      }
    }
#pragma unroll
    for (int c = 0; c < 8; ++c) {
      float w0_ = w1[c * 9 + 0], w1_ = w1[c * 9 + 1], w2_ = w1[c * 9 + 2],
            w3_ = w1[c * 9 + 3], w4_ = w1[c * 9 + 4], w5_ = w1[c * 9 + 5],
            w6_ = w1[c * 9 + 6], w7_ = w1[c * 9 + 7], w8_ = w1[c * 9 + 8];
      float s00 = C9(0, 0), s01 = C9(0, 1), s10 = C9(1, 0), s11 = C9(1, 1);
      float m = fmaxf(fmaxf(s00, s01), fmaxf(s10, s11));
      hs[(c * NROWS + r) * HSTR + 1 + hc] = fmaxf(m + b1[c], 0.f);
    }
  }
  __syncthreads();

  // ---- Phase 2: conv2+bias+relu+pool + patch contribution ----
  // wave q -> oc 4q..4q+3 (weights wave-uniform -> SGPR). lane l sweeps
  // pixels pix = pass*64+l; fx-major => LDS float2 reads stride 2 = free.
  {
    const int q = tid >> 6, l = tid & 63;
    const float* wq = w2 + q * 4 * 72;  // (oc*8+ic)*9, oc = 4q+o
#pragma unroll 1
    for (int pass = 0; pass < 7; ++pass) {
      int pix = pass * 64 + l;
      if (pix < 392) {
        int fy = pix / 28, fx = pix % 28;  // tile-local f-row, f-col
        int r0 = 2 * fy, c0 = 2 * fx;      // window top/left (tile coords)
        float a[4][4];
#pragma unroll
        for (int o = 0; o < 4; ++o)
#pragma unroll
          for (int qq = 0; qq < 4; ++qq) a[o][qq] = 0.f;
#pragma unroll 1
        for (int ic = 0; ic < 8; ++ic) {
          float win[4][4];
          const float* hb_ = hs + (ic * NROWS + r0) * HSTR + c0;
#pragma unroll
          for (int jj = 0; jj < 4; ++jj) {
            float2 u = *(const float2*)(hb_ + jj * HSTR);
            float2 v = *(const float2*)(hb_ + jj * HSTR + 2);
            win[jj][0] = u.x; win[jj][1] = u.y;
            win[jj][2] = v.x; win[jj][3] = v.y;
          }
#pragma unroll
          for (int o = 0; o < 4; ++o) {
            const float* wt = wq + (o * 8 + ic) * 9;  // wave-uniform -> s_load
            float w0_ = wt[0], w1_ = wt[1], w2_ = wt[2], w3_ = wt[3],
                  w4_ = wt[4], w5_ = wt[5], w6_ = wt[6], w7_ = wt[7],
                  w8_ = wt[8];
            a[o][0] += C9(0, 0);
            a[o][1] += C9(0, 1);
            a[o][2] += C9(1, 0);
            a[o][3] += C9(1, 1);
          }
        }
        int dy = fy & 1, dx = fx & 1;  // global parity == local (14s even)
        float partial[4] = {0.f, 0.f, 0.f, 0.f};
#pragma unroll
        for (int o = 0; o < 4; ++o) {
          int oc = 4 * q + o;
          float m = fmaxf(fmaxf(a[o][0], a[o][1]), fmaxf(a[o][2], a[o][3]));
          float fv = fmaxf(m + b2[oc], 0.f);  // f[oc][fy][fx]
#pragma unroll
          for (int ot = 0; ot < 4; ++ot)
            partial[ot] += fv * wp[ot * 64 + oc * 4 + dy * 2 + dx];
        }
        int p_l = (fy >> 1) * 14 + (fx >> 1);
#pragma unroll
        for (int ot = 0; ot < 4; ++ot)
          atomicAdd(&pfp[p_l * 4 + ot], partial[ot]);
      }
    }
  }
  __syncthreads();

  // ---- Phase 3: fc1 partial over this tile's pf slice [392s, 392s+392) ----
  {
    int j = tid >> 2, q4 = tid & 3;
    const float2* wrow = (const float2*)(w_fc1 + j * 784 + 392 * s + q4 * 98);
    const float2* pv = (const float2*)(pfp + q4 * 98);
    float acc = 0.f;
#pragma unroll 7
    for (int m = 0; m < 49; ++m) {
      float2 wv = wrow[m], fv = pv[m];
      acc += wv.x * fv.x + wv.y * fv.y;
    }
    acc += __shfl_down(acc, 2, 4);
    acc += __shfl_down(acc, 1, 4);
    if (q4 == 0) h1p[((long)b * 2 + s) * 64 + j] = acc;
  }
}

// ---------------- k_tail: combine partials + fc2 + log_softmax --------------
__global__ __launch_bounds__(64) void k_tail(const float* __restrict__ h1p,
                                             const float* __restrict__ b_fc1,
                                             const float* __restrict__ w_fc2,
                                             const float* __restrict__ b_fc2,
                                             float* __restrict__ out) {
  __shared__ float h1s[64];
  __shared__ float red[11];  // [0..9] logits, [10] lse
  int b = blockIdx.x, j = threadIdx.x;
  float v = b_fc1[j] + h1p[(long)b * 128 + j] + h1p[(long)b * 128 + 64 + j];
  h1s[j] = fmaxf(v, 0.f);
  __syncthreads();
  if (j < 10) {
    float acc = b_fc2[j];
    const float* wo = w_fc2 + j * 64;
#pragma unroll
    for (int k = 0; k < 64; ++k) acc += h1s[k] * wo[k];
    red[j] = acc;
  }
  __syncthreads();
  if (j == 0) {
    float mx = red[0];
    for (int o = 1; o < 10; ++o) mx = fmaxf(mx, red[o]);
    float se = 0.f;
    for (int o = 0; o < 10; ++o) se += expf(red[o] - mx);
    red[10] = mx + logf(se);
  }
  __syncthreads();
  if (j < 10) out[b * 10 + j] = red[j] - red[10];
}

extern "C" void kernel_launch(void* const* d_in, const int* in_sizes, int n_in,
                              void* d_out, int out_size, void* d_ws, size_t ws_size,
                              hipStream_t stream) {
  const float* x = (const float*)d_in[0];
  const float* w1 = (const float*)d_in[1];
  const float* b1 = (const float*)d_in[2];
  const float* w2 = (const float*)d_in[3];
  const float* b2 = (const float*)d_in[4];
  const float* wp = (const float*)d_in[5];
  const float* bp = (const float*)d_in[6];
  const float* wf1 = (const float*)d_in[7];
  const float* bf1 = (const float*)d_in[8];
  const float* wf2 = (const float*)d_in[9];
  const float* bf2 = (const float*)d_in[10];

  float* h1p = (float*)d_ws;  // [512][2][64] fc1 partials = 256 KB

  k_fused<<<dim3(1024), 256, 0, stream>>>(x, w1, b1, w2, b2, wp, bp, wf1, h1p);
  k_tail<<<dim3(512), 64, 0, stream>>>(h1p, bf1, wf2, bf2, (float*)d_out);
}

// Round 9
// 172.966 us; speedup vs baseline: 1.2410x; 1.2410x over previous
//
#include <hip/hip_runtime.h>

// Single fused kernel: block = one batch element, 256 threads, 2 blocks/CU.
//   loop s=0,1 (f-rows 14s..14s+13):
//     P1 conv1+relu+pool -> LDS h-tile[8][30][58] (h-rows 28s-1..28s+28, zero halo)
//     P2 conv2+relu+pool: wave q -> oc 4q..4q+3 (weights via readfirstlane ->
//        s_load). Task t: u=t>>1 selects (patch-row, fx), dy=t&1. shfl_xor(1)
//        combines dy pair, shfl_xor(2) combines dx pair -> quad leader writes
//        pfh[q][p][4]. 392 tasks / 7 passes of 64 lanes. No atomics.
//     P3 pfl[392] = bp + sum_q pfh (overlaid on dead hs region)
//        fc1 partial: h1a[64] (+)= w_fc1[:, 392s..] . pfl
//   tail: relu(h1a+b_fc1) -> fc2 -> log_softmax -> out[512,10]
// All fp32. h, f, pf, h1 never touch HBM. d_ws unused.

#define HSTR 58   // 56 cols + 2 halo cols; even -> float2-aligned
#define NROWS 30  // 28 tile h-rows + 2 halo

#define C9(J, K)                                                             \
  (win[J][K] * w0_ + win[J][K + 1] * w1_ + win[J][K + 2] * w2_ +             \
   win[J + 1][K] * w3_ + win[J + 1][K + 1] * w4_ + win[J + 1][K + 2] * w5_ + \
   win[J + 2][K] * w6_ + win[J + 2][K + 1] * w7_ + win[J + 2][K + 2] * w8_)

__global__ __launch_bounds__(256, 2) void k_all(
    const float* __restrict__ x, const float* __restrict__ w1,
    const float* __restrict__ b1, const float* __restrict__ w2,
    const float* __restrict__ b2, const float* __restrict__ wp,
    const float* __restrict__ bp, const float* __restrict__ w_fc1,
    const float* __restrict__ b_fc1, const float* __restrict__ w_fc2,
    const float* __restrict__ b_fc2, float* __restrict__ out) {
  __shared__ __align__(16) float hs[8 * NROWS * HSTR];  // 13920 f = 55.7 KB
  __shared__ __align__(16) float pfh[4 * 98 * 4];       // [q][p_l][ot] 6.3 KB
  __shared__ float h1a[64];
  __shared__ float red[11];
  const int tid = threadIdx.x;
  const int b = blockIdx.x;
  const int l = tid & 63;
  const int qs = __builtin_amdgcn_readfirstlane(tid >> 6);  // wave id -> SGPR
  const float* xb = x + (long)b * 12544;                    // x[b], 112x112
  const float* wq = w2 + qs * 288;                          // oc-quad weights
  float b2q[4];
#pragma unroll
  for (int o = 0; o < 4; ++o) b2q[o] = b2[qs * 4 + o];

#pragma unroll 1
  for (int s = 0; s < 2; ++s) {
    for (int i = tid; i < 8 * NROWS * HSTR; i += 256) hs[i] = 0.f;
    __syncthreads();

    // ---- P1: conv1(1->8)+bias+relu+maxpool2 into LDS tile ----
    // tile row r 0..29 <-> global pooled-h row gr = 28s-1+r; halo stays 0.
    for (int task = tid; task < 1680; task += 256) {
      int r = task / 56, hc = task % 56;
      int gr = 28 * s - 1 + r;
      if ((unsigned)gr >= 56u) continue;
      float win[4][4];
      int iy0 = 2 * gr - 1, ix0 = 2 * hc - 1;
#pragma unroll
      for (int rr = 0; rr < 4; ++rr) {
        int iy = iy0 + rr;
        bool yok = (unsigned)iy < 112u;
#pragma unroll
        for (int qq = 0; qq < 4; ++qq) {
          int ix = ix0 + qq;
          win[rr][qq] = (yok && (unsigned)ix < 112u) ? xb[iy * 112 + ix] : 0.f;
        }
      }
#pragma unroll
      for (int c = 0; c < 8; ++c) {
        float w0_ = w1[c * 9 + 0], w1_ = w1[c * 9 + 1], w2_ = w1[c * 9 + 2],
              w3_ = w1[c * 9 + 3], w4_ = w1[c * 9 + 4], w5_ = w1[c * 9 + 5],
              w6_ = w1[c * 9 + 6], w7_ = w1[c * 9 + 7], w8_ = w1[c * 9 + 8];
        float s00 = C9(0, 0), s01 = C9(0, 1), s10 = C9(1, 0), s11 = C9(1, 1);
        float m = fmaxf(fmaxf(s00, s01), fmaxf(s10, s11));
        hs[(c * NROWS + r) * HSTR + 1 + hc] = fmaxf(m + b1[c], 0.f);
      }
    }
    __syncthreads();

    // ---- P2: conv2+bias+relu+pool + patch combine via shfl ----
    // task t: u=t>>1, dy=t&1; pixel (fy=2*(u/28)+dy, fx=u%28), oc 4qs..4qs+3.
    // lanes l^1 share u (dy pair); lanes l^2 share patch row, fx pair.
#pragma unroll 1
    for (int pass = 0; pass < 7; ++pass) {
      int t = pass * 64 + l;
      if (t < 392) {
        int u = t >> 1, dyt = t & 1;
        int pr = u / 28, fx = u - 28 * pr;
        int fy = 2 * pr + dyt;
        int r0 = 2 * fy, c0 = 2 * fx;  // window top/left (tile coords)
        float a[4][4];
#pragma unroll
        for (int o = 0; o < 4; ++o)
#pragma unroll
          for (int qq = 0; qq < 4; ++qq) a[o][qq] = 0.f;
#pragma unroll 1
        for (int ic = 0; ic < 8; ++ic) {
          float win[4][4];
          const float* hb_ = hs + (ic * NROWS + r0) * HSTR + c0;
#pragma unroll
          for (int jj = 0; jj < 4; ++jj) {
            float2 uu = *(const float2*)(hb_ + jj * HSTR);
            float2 vv = *(const float2*)(hb_ + jj * HSTR + 2);
            win[jj][0] = uu.x; win[jj][1] = uu.y;
            win[jj][2] = vv.x; win[jj][3] = vv.y;
          }
#pragma unroll
          for (int o = 0; o < 4; ++o) {
            const float* wt = wq + (o * 8 + ic) * 9;  // SGPR base -> s_load
            float w0_ = wt[0], w1_ = wt[1], w2_ = wt[2], w3_ = wt[3],
                  w4_ = wt[4], w5_ = wt[5], w6_ = wt[6], w7_ = wt[7],
                  w8_ = wt[8];
            a[o][0] += C9(0, 0);
            a[o][1] += C9(0, 1);
            a[o][2] += C9(1, 0);
            a[o][3] += C9(1, 1);
          }
        }
        int dx = fx & 1;
        float partial[4] = {0.f, 0.f, 0.f, 0.f};
#pragma unroll
        for (int o = 0; o < 4; ++o) {
          float m = fmaxf(fmaxf(a[o][0], a[o][1]), fmaxf(a[o][2], a[o][3]));
          float fv = fmaxf(m + b2q[o], 0.f);  // f[4qs+o][fy][fx]
#pragma unroll
          for (int ot = 0; ot < 4; ++ot)
            partial[ot] +=
                fv * wp[ot * 64 + (qs * 4 + o) * 4 + dyt * 2 + dx];
        }
#pragma unroll
        for (int ot = 0; ot < 4; ++ot) {
          partial[ot] += __shfl_xor(partial[ot], 1, 64);  // dy pair
          partial[ot] += __shfl_xor(partial[ot], 2, 64);  // dx pair
        }
        if ((l & 3) == 0) {
          int p_l = pr * 14 + (fx >> 1);
          *(float4*)&pfh[(qs * 98 + p_l) * 4] =
              make_float4(partial[0], partial[1], partial[2], partial[3]);
        }
      }
    }
    __syncthreads();

    // ---- P3a: pfl = bp + sum_q pfh  (overlay on dead hs) ----
    float* pfl = hs;
    for (int t2 = tid; t2 < 392; t2 += 256) {
      int p = t2 >> 2, ot = t2 & 3;
      pfl[t2] = bp[ot] + pfh[(0 * 98 + p) * 4 + ot] + pfh[(1 * 98 + p) * 4 + ot] +
                pfh[(2 * 98 + p) * 4 + ot] + pfh[(3 * 98 + p) * 4 + ot];
    }
    __syncthreads();

    // ---- P3b: fc1 partial over pf slice [392s, 392s+392) ----
    {
      int j = tid >> 2, q4 = tid & 3;
      const float2* wrow = (const float2*)(w_fc1 + j * 784 + 392 * s + q4 * 98);
      const float2* pv = (const float2*)(pfl + q4 * 98);
      float acc = 0.f;
#pragma unroll 7
      for (int m = 0; m < 49; ++m) {
        float2 wv = wrow[m], fv = pv[m];
        acc += wv.x * fv.x + wv.y * fv.y;
      }
      acc += __shfl_down(acc, 2, 4);
      acc += __shfl_down(acc, 1, 4);
      if (q4 == 0) {
        if (s == 0) h1a[j] = acc;
        else h1a[j] += acc;
      }
    }
    __syncthreads();
  }

  // ---- tail: relu + fc2 + log_softmax ----
  if (tid < 64) h1a[tid] = fmaxf(h1a[tid] + b_fc1[tid], 0.f);
  __syncthreads();
  if (tid < 10) {
    float acc = b_fc2[tid];
    const float* wo = w_fc2 + tid * 64;
#pragma unroll
    for (int k = 0; k < 64; ++k) acc += h1a[k] * wo[k];
    red[tid] = acc;
  }
  __syncthreads();
  if (tid == 0) {
    float mx = red[0];
    for (int o = 1; o < 10; ++o) mx = fmaxf(mx, red[o]);
    float se = 0.f;
    for (int o = 0; o < 10; ++o) se += expf(red[o] - mx);
    red[10] = mx + logf(se);
  }
  __syncthreads();
  if (tid < 10) out[b * 10 + tid] = red[tid] - red[10];
}

extern "C" void kernel_launch(void* const* d_in, const int* in_sizes, int n_in,
                              void* d_out, int out_size, void* d_ws, size_t ws_size,
                              hipStream_t stream) {
  const float* x = (const float*)d_in[0];
  const float* w1 = (const float*)d_in[1];
  const float* b1 = (const float*)d_in[2];
  const float* w2 = (const float*)d_in[3];
  const float* b2 = (const float*)d_in[4];
  const float* wp = (const float*)d_in[5];
  const float* bp = (const float*)d_in[6];
  const float* wf1 = (const float*)d_in[7];
  const float* bf1 = (const float*)d_in[8];
  const float* wf2 = (const float*)d_in[9];
  const float* bf2 = (const float*)d_in[10];

  k_all<<<dim3(512), 256, 0, stream>>>(x, w1, b1, w2, b2, wp, bp, wf1, bf1,
                                       wf2, bf2, (float*)d_out);
}

// Round 10
// 157.416 us; speedup vs baseline: 1.3636x; 1.0988x over previous
//
#include <hip/hip_runtime.h>

// Fused pipeline, bf16-packed LDS h-tile:
//   k_fused (grid 1024 = b*2+s, 256 thr, 4 blocks/CU):
//     P1 conv1+relu+pool -> LDS h-tile, bf16 ic-pairs packed in u32:
//        hsu[icp=4][30 rows][58 cols] (h-rows 28s-1..28s+28, zero halo)
//     P2 conv2+relu+pool: wave q = oc-quad (readfirstlane -> SGPR weights);
//        7 passes x 56 lanes = 2 f-rows/pass; shfl_xor(1) combines dx,
//        shfl(l+-28) combines dy -> leader writes pfq[q][98][4]. No atomics.
//     P3 pfl = bp + sum_q pfq (overlay dead hs); fc1 partial -> h1p[b][s][64]
//   k_tail: h1 = relu(sum_s h1p + b_fc1); fc2; log_softmax -> out[512,10]

#define HSTR 58   // 56 cols + 2 halo cols (u32 units)
#define NROWS 30  // 28 tile h-rows + 2 halo

#define C9W(W, J, K)                                                      \
  (W[J][K] * w0_ + W[J][K + 1] * w1_ + W[J][K + 2] * w2_ + W[J + 1][K] * w3_ + \
   W[J + 1][K + 1] * w4_ + W[J + 1][K + 2] * w5_ + W[J + 2][K] * w6_ +    \
   W[J + 2][K + 1] * w7_ + W[J + 2][K + 2] * w8_)

__device__ __forceinline__ unsigned pack_bf16(float a, float b) {
  unsigned ua = (__float_as_uint(a) + 0x8000u) >> 16;   // round-half-up
  unsigned ub = (__float_as_uint(b) + 0x8000u) & 0xffff0000u;
  return ua | ub;
}

__global__ __launch_bounds__(256, 4) void k_fused(
    const float* __restrict__ x, const float* __restrict__ w1,
    const float* __restrict__ b1, const float* __restrict__ w2,
    const float* __restrict__ b2, const float* __restrict__ wp,
    const float* __restrict__ bp, const float* __restrict__ w_fc1,
    float* __restrict__ h1p) {
  __shared__ __align__(16) unsigned hsu[4 * NROWS * HSTR];  // 27.8 KB
  __shared__ __align__(16) float pfq[4 * 98 * 4];           // 6.3 KB
  const int tid = threadIdx.x;
  const int b = blockIdx.x >> 1;
  const int s = blockIdx.x & 1;
  const int l = tid & 63;
  const int qs = __builtin_amdgcn_readfirstlane(tid >> 6);  // wave id 0..3
  const float* xb = x + (long)b * 12544;
  const float* wq = w2 + qs * 288;  // oc-quad weights (SGPR base)
  float b2q[4];
#pragma unroll
  for (int o = 0; o < 4; ++o) b2q[o] = b2[qs * 4 + o];

  for (int i = tid; i < 4 * NROWS * HSTR; i += 256) hsu[i] = 0u;
  __syncthreads();

  // ---- P1: conv1(1->8)+bias+relu+maxpool2 -> bf16-packed LDS tile ----
  // tile row r 0..29 <-> global pooled-h row gr = 28s-1+r; halo stays 0.
  for (int task = tid; task < 1680; task += 256) {
    int r = task / 56, hc = task % 56;
    int gr = 28 * s - 1 + r;
    if ((unsigned)gr >= 56u) continue;
    float win[4][4];
    int iy0 = 2 * gr - 1, ix0 = 2 * hc - 1;
#pragma unroll
    for (int rr = 0; rr < 4; ++rr) {
      int iy = iy0 + rr;
      bool yok = (unsigned)iy < 112u;
#pragma unroll
      for (int qq = 0; qq < 4; ++qq) {
        int ix = ix0 + qq;
        win[rr][qq] = (yok && (unsigned)ix < 112u) ? xb[iy * 112 + ix] : 0.f;
      }
    }
    float hv[8];
#pragma unroll
    for (int c = 0; c < 8; ++c) {
      float w0_ = w1[c * 9 + 0], w1_ = w1[c * 9 + 1], w2_ = w1[c * 9 + 2],
            w3_ = w1[c * 9 + 3], w4_ = w1[c * 9 + 4], w5_ = w1[c * 9 + 5],
            w6_ = w1[c * 9 + 6], w7_ = w1[c * 9 + 7], w8_ = w1[c * 9 + 8];
      float s00 = C9W(win, 0, 0), s01 = C9W(win, 0, 1), s10 = C9W(win, 1, 0),
            s11 = C9W(win, 1, 1);
      float m = fmaxf(fmaxf(s00, s01), fmaxf(s10, s11));
      hv[c] = fmaxf(m + b1[c], 0.f);
    }
#pragma unroll
    for (int cp = 0; cp < 4; ++cp)
      hsu[(cp * NROWS + r) * HSTR + 1 + hc] = pack_bf16(hv[2 * cp], hv[2 * cp + 1]);
  }
  __syncthreads();

  // ---- P2: conv2+bias+relu+pool + patch-linear, shfl combine ----
  // pass p: 56 lanes cover f-rows 2p (lanes 0..27) and 2p+1 (lanes 28..55).
#pragma unroll 1
  for (int pass = 0; pass < 7; ++pass) {
    float partial[4] = {0.f, 0.f, 0.f, 0.f};
    int dy = (l >= 28) ? 1 : 0;
    int fx = l - 28 * dy;  // 0..27 (junk for l>=56, masked below)
    if (l < 56) {
      int fy = 2 * pass + dy;
      int r0 = 2 * fy, c0 = 2 * fx;
      float a[4][4];
#pragma unroll
      for (int o = 0; o < 4; ++o)
#pragma unroll
        for (int qq = 0; qq < 4; ++qq) a[o][qq] = 0.f;
#pragma unroll 1
      for (int cp = 0; cp < 4; ++cp) {  // ic pair 2cp, 2cp+1
        float wlo[4][4], whi[4][4];
        const unsigned* hb_ = hsu + (cp * NROWS + r0) * HSTR + c0;
#pragma unroll
        for (int jj = 0; jj < 4; ++jj) {
          uint2 u = *(const uint2*)(hb_ + jj * HSTR);
          uint2 v = *(const uint2*)(hb_ + jj * HSTR + 2);
          wlo[jj][0] = __uint_as_float(u.x << 16);
          whi[jj][0] = __uint_as_float(u.x & 0xffff0000u);
          wlo[jj][1] = __uint_as_float(u.y << 16);
          whi[jj][1] = __uint_as_float(u.y & 0xffff0000u);
          wlo[jj][2] = __uint_as_float(v.x << 16);
          whi[jj][2] = __uint_as_float(v.x & 0xffff0000u);
          wlo[jj][3] = __uint_as_float(v.y << 16);
          whi[jj][3] = __uint_as_float(v.y & 0xffff0000u);
        }
#pragma unroll
        for (int o = 0; o < 4; ++o) {
          {
            const float* wt = wq + (o * 8 + 2 * cp) * 9;  // SGPR -> s_load
            float w0_ = wt[0], w1_ = wt[1], w2_ = wt[2], w3_ = wt[3],
                  w4_ = wt[4], w5_ = wt[5], w6_ = wt[6], w7_ = wt[7],
                  w8_ = wt[8];
            a[o][0] += C9W(wlo, 0, 0);
            a[o][1] += C9W(wlo, 0, 1);
            a[o][2] += C9W(wlo, 1, 0);
            a[o][3] += C9W(wlo, 1, 1);
          }
          {
            const float* wt = wq + (o * 8 + 2 * cp + 1) * 9;
            float w0_ = wt[0], w1_ = wt[1], w2_ = wt[2], w3_ = wt[3],
                  w4_ = wt[4], w5_ = wt[5], w6_ = wt[6], w7_ = wt[7],
                  w8_ = wt[8];
            a[o][0] += C9W(whi, 0, 0);
            a[o][1] += C9W(whi, 0, 1);
            a[o][2] += C9W(whi, 1, 0);
            a[o][3] += C9W(whi, 1, 1);
          }
        }
      }
      int dx = fx & 1;
#pragma unroll
      for (int o = 0; o < 4; ++o) {
        float m = fmaxf(fmaxf(a[o][0], a[o][1]), fmaxf(a[o][2], a[o][3]));
        float fv = fmaxf(m + b2q[o], 0.f);  // f[4qs+o][fy][fx]
#pragma unroll
        for (int ot = 0; ot < 4; ++ot)
          partial[ot] += fv * wp[ot * 64 + (qs * 4 + o) * 4 + dy * 2 + dx];
      }
    }
    // combine dx pair (l^1), then dy pair (l +- 28); leaders write slot.
#pragma unroll
    for (int ot = 0; ot < 4; ++ot) {
      partial[ot] += __shfl_xor(partial[ot], 1, 64);
      partial[ot] += __shfl(partial[ot], (l < 28) ? (l + 28) : (l - 28), 64);
    }
    if (l < 28 && (l & 1) == 0) {
      int p = pass * 14 + (fx >> 1);
      *(float4*)&pfq[(qs * 98 + p) * 4] =
          make_float4(partial[0], partial[1], partial[2], partial[3]);
    }
  }
  __syncthreads();

  // ---- P3a: pfl = bp + sum_q pfq (overlay on dead hs region) ----
  float* pfl = (float*)hsu;
  for (int t2 = tid; t2 < 392; t2 += 256) {
    int p = t2 >> 2, ot = t2 & 3;
    pfl[t2] = bp[ot] + pfq[(0 * 98 + p) * 4 + ot] + pfq[(1 * 98 + p) * 4 + ot] +
              pfq[(2 * 98 + p) * 4 + ot] + pfq[(3 * 98 + p) * 4 + ot];
  }
  __syncthreads();

  // ---- P3b: fc1 partial over pf slice [392s, 392s+392) ----
  {
    int j = tid >> 2, q4 = tid & 3;
    const float2* wrow = (const float2*)(w_fc1 + j * 784 + 392 * s + q4 * 98);
    const float2* pv = (const float2*)(pfl + q4 * 98);
    float acc = 0.f;
#pragma unroll 7
    for (int m = 0; m < 49; ++m) {
      float2 wv = wrow[m], fv = pv[m];
      acc += wv.x * fv.x + wv.y * fv.y;
    }
    acc += __shfl_down(acc, 2, 4);
    acc += __shfl_down(acc, 1, 4);
    if (q4 == 0) h1p[((long)b * 2 + s) * 64 + j] = acc;
  }
}

// ---------------- k_tail: combine partials + fc2 + log_softmax --------------
__global__ __launch_bounds__(64) void k_tail(const float* __restrict__ h1p,
                                             const float* __restrict__ b_fc1,
                                             const float* __restrict__ w_fc2,
                                             const float* __restrict__ b_fc2,
                                             float* __restrict__ out) {
  __shared__ float h1s[64];
  __shared__ float red[11];
  int b = blockIdx.x, j = threadIdx.x;
  float v = b_fc1[j] + h1p[(long)b * 128 + j] + h1p[(long)b * 128 + 64 + j];
  h1s[j] = fmaxf(v, 0.f);
  __syncthreads();
  if (j < 10) {
    float acc = b_fc2[j];
    const float* wo = w_fc2 + j * 64;
#pragma unroll
    for (int k = 0; k < 64; ++k) acc += h1s[k] * wo[k];
    red[j] = acc;
  }
  __syncthreads();
  if (j == 0) {
    float mx = red[0];
    for (int o = 1; o < 10; ++o) mx = fmaxf(mx, red[o]);
    float se = 0.f;
    for (int o = 0; o < 10; ++o) se += expf(red[o] - mx);
    red[10] = mx + logf(se);
  }
  __syncthreads();
  if (j < 10) out[b * 10 + j] = red[j] - red[10];
}

extern "C" void kernel_launch(void* const* d_in, const int* in_sizes, int n_in,
                              void* d_out, int out_size, void* d_ws, size_t ws_size,
                              hipStream_t stream) {
  const float* x = (const float*)d_in[0];
  const float* w1 = (const float*)d_in[1];
  const float* b1 = (const float*)d_in[2];
  const float* w2 = (const float*)d_in[3];
  const float* b2 = (const float*)d_in[4];
  const float* wp = (const float*)d_in[5];
  const float* bp = (const float*)d_in[6];
  const float* wf1 = (const float*)d_in[7];
  const float* bf1 = (const float*)d_in[8];
  const float* wf2 = (const float*)d_in[9];
  const float* bf2 = (const float*)d_in[10];

  float* h1p = (float*)d_ws;  // [512][2][64] fc1 partials = 256 KB

  k_fused<<<dim3(1024), 256, 0, stream>>>(x, w1, b1, w2, b2, wp, bp, wf1, h1p);
  k_tail<<<dim3(512), 64, 0, stream>>>(h1p, bf1, wf2, bf2, (float*)d_out);
}

// Round 11
// 151.577 us; speedup vs baseline: 1.4161x; 1.0385x over previous
//
#include <hip/hip_runtime.h>

// Fused pipeline, f16-packed LDS h-tile + v_dot2_f32_f16 conv2:
//   k_prew: pack w2 -> pw u32[16][4][9] (f16 ic-pairs) in ws
//   k_fused (grid 1024 = b*2+s, 256 thr, 4 blocks/CU):
//     P1 conv1+relu+pool (fp32) -> LDS h-tile, f16 ic-pairs in u32:
//        hsu[icp=4][30 rows][58 cols] (h-rows 28s-1..28s+28, zero halo)
//     P2 conv2+relu+pool via fdot2 (2 MAC/inst, no unpack); wave q = oc-quad,
//        packed weights via SGPR s_load; 7 passes x 56 lanes = 2 f-rows/pass;
//        shfl_xor(1) combines dx, shfl(l+-28) combines dy -> pfq[q][98][4].
//     P3 pfl = bp + sum_q pfq (overlay dead hs); fc1 partial -> h1p[b][s][64]
//   k_tail: h1 = relu(sum_s h1p + b_fc1); fc2; log_softmax -> out[512,10]

#define HSTR 58   // 56 cols + 2 halo cols (u32 units)
#define NROWS 30  // 28 tile h-rows + 2 halo

typedef _Float16 half2_t __attribute__((ext_vector_type(2)));

__device__ __forceinline__ unsigned pack_f16(float a, float b) {
  union { half2_t h; unsigned u; } z;
  z.h[0] = (_Float16)a;
  z.h[1] = (_Float16)b;
  return z.u;
}

__device__ __forceinline__ half2_t as_h2(unsigned u) {
  union { unsigned u; half2_t h; } z;
  z.u = u;
  return z.h;
}

__device__ __forceinline__ float fdot2_(half2_t a, half2_t b, float c) {
#if __has_builtin(__builtin_amdgcn_fdot2)
  return __builtin_amdgcn_fdot2(a, b, c, false);
#else
  return c + (float)a[0] * (float)b[0] + (float)a[1] * (float)b[1];
#endif
}

// fp32 9-tap conv dot (P1)
#define C9W(W, J, K)                                                           \
  (W[J][K] * w0_ + W[J][K + 1] * w1_ + W[J][K + 2] * w2_ + W[J + 1][K] * w3_ + \
   W[J + 1][K + 1] * w4_ + W[J + 1][K + 2] * w5_ + W[J + 2][K] * w6_ +         \
   W[J + 2][K + 1] * w7_ + W[J + 2][K + 2] * w8_)

// f16-pair 9-tap conv dot via fdot2 (P2): acc over win2[J..J+2][K..K+2]
#define D9(ACC, J, K)                                                   \
  do {                                                                  \
    float t_ = ACC;                                                     \
    t_ = fdot2_(win2[J][K], wt0, t_);                                   \
    t_ = fdot2_(win2[J][K + 1], wt1, t_);                               \
    t_ = fdot2_(win2[J][K + 2], wt2, t_);                               \
    t_ = fdot2_(win2[J + 1][K], wt3, t_);                               \
    t_ = fdot2_(win2[J + 1][K + 1], wt4, t_);                           \
    t_ = fdot2_(win2[J + 1][K + 2], wt5, t_);                           \
    t_ = fdot2_(win2[J + 2][K], wt6, t_);                               \
    t_ = fdot2_(win2[J + 2][K + 1], wt7, t_);                           \
    t_ = fdot2_(win2[J + 2][K + 2], wt8, t_);                           \
    ACC = t_;                                                           \
  } while (0)

// ---------------- k_prew: pack conv2 weights as f16 ic-pairs ---------------
// pw[(oc*4+cp)*9+k] = f16pair(w2[oc][2cp][k], w2[oc][2cp+1][k])
__global__ __launch_bounds__(256) void k_prew(const float* __restrict__ w2,
                                              unsigned* __restrict__ pw) {
  int t = blockIdx.x * 256 + threadIdx.x;
  if (t < 576) {
    int k = t % 9;
    int rest = t / 9;
    int cp = rest & 3, oc = rest >> 2;
    pw[t] = pack_f16(w2[(oc * 8 + 2 * cp) * 9 + k],
                     w2[(oc * 8 + 2 * cp + 1) * 9 + k]);
  }
}

__global__ __launch_bounds__(256, 4) void k_fused(
    const float* __restrict__ x, const float* __restrict__ w1,
    const float* __restrict__ b1, const unsigned* __restrict__ pw,
    const float* __restrict__ b2, const float* __restrict__ wp,
    const float* __restrict__ bp, const float* __restrict__ w_fc1,
    float* __restrict__ h1p) {
  __shared__ __align__(16) unsigned hsu[4 * NROWS * HSTR];  // 27.8 KB
  __shared__ __align__(16) float pfq[4 * 98 * 4];           // 6.3 KB
  const int tid = threadIdx.x;
  const int b = blockIdx.x >> 1;
  const int s = blockIdx.x & 1;
  const int l = tid & 63;
  const int qs = __builtin_amdgcn_readfirstlane(tid >> 6);  // wave id 0..3
  const float* xb = x + (long)b * 12544;
  const unsigned* pwq = pw + qs * 144;  // this wave's oc-quad packed weights
  float b2q[4];
#pragma unroll
  for (int o = 0; o < 4; ++o) b2q[o] = b2[qs * 4 + o];

  for (int i = tid; i < 4 * NROWS * HSTR; i += 256) hsu[i] = 0u;
  __syncthreads();

  // ---- P1: conv1(1->8)+bias+relu+maxpool2 -> f16-packed LDS tile ----
  // tile row r 0..29 <-> global pooled-h row gr = 28s-1+r; halo stays 0.
  for (int task = tid; task < 1680; task += 256) {
    int r = task / 56, hc = task % 56;
    int gr = 28 * s - 1 + r;
    if ((unsigned)gr >= 56u) continue;
    float win[4][4];
    int iy0 = 2 * gr - 1, ix0 = 2 * hc - 1;
#pragma unroll
    for (int rr = 0; rr < 4; ++rr) {
      int iy = iy0 + rr;
      bool yok = (unsigned)iy < 112u;
#pragma unroll
      for (int qq = 0; qq < 4; ++qq) {
        int ix = ix0 + qq;
        win[rr][qq] = (yok && (unsigned)ix < 112u) ? xb[iy * 112 + ix] : 0.f;
      }
    }
    float hv[8];
#pragma unroll
    for (int c = 0; c < 8; ++c) {
      float w0_ = w1[c * 9 + 0], w1_ = w1[c * 9 + 1], w2_ = w1[c * 9 + 2],
            w3_ = w1[c * 9 + 3], w4_ = w1[c * 9 + 4], w5_ = w1[c * 9 + 5],
            w6_ = w1[c * 9 + 6], w7_ = w1[c * 9 + 7], w8_ = w1[c * 9 + 8];
      float s00 = C9W(win, 0, 0), s01 = C9W(win, 0, 1), s10 = C9W(win, 1, 0),
            s11 = C9W(win, 1, 1);
      float m = fmaxf(fmaxf(s00, s01), fmaxf(s10, s11));
      hv[c] = fmaxf(m + b1[c], 0.f);
    }
#pragma unroll
    for (int cp = 0; cp < 4; ++cp)
      hsu[(cp * NROWS + r) * HSTR + 1 + hc] = pack_f16(hv[2 * cp], hv[2 * cp + 1]);
  }
  __syncthreads();

  // ---- P2: conv2+bias+relu+pool via fdot2 + patch-linear, shfl combine ----
  // pass p: 56 lanes cover f-rows 2p (lanes 0..27) and 2p+1 (lanes 28..55).
#pragma unroll 1
  for (int pass = 0; pass < 7; ++pass) {
    float partial[4] = {0.f, 0.f, 0.f, 0.f};
    int dy = (l >= 28) ? 1 : 0;
    int fx = l - 28 * dy;  // 0..27 (junk for l>=56, masked below)
    if (l < 56) {
      int fy = 2 * pass + dy;
      int r0 = 2 * fy, c0 = 2 * fx;
      float a[4][4];
#pragma unroll
      for (int o = 0; o < 4; ++o)
#pragma unroll
        for (int qq = 0; qq < 4; ++qq) a[o][qq] = 0.f;
#pragma unroll 1
      for (int cp = 0; cp < 4; ++cp) {  // ic pair 2cp, 2cp+1
        half2_t win2[4][4];
        const unsigned* hb_ = hsu + (cp * NROWS + r0) * HSTR + c0;
#pragma unroll
        for (int jj = 0; jj < 4; ++jj) {
          uint2 u = *(const uint2*)(hb_ + jj * HSTR);
          uint2 v = *(const uint2*)(hb_ + jj * HSTR + 2);
          win2[jj][0] = as_h2(u.x);
          win2[jj][1] = as_h2(u.y);
          win2[jj][2] = as_h2(v.x);
          win2[jj][3] = as_h2(v.y);
        }
#pragma unroll
        for (int o = 0; o < 4; ++o) {
          const unsigned* wt = pwq + o * 36 + cp * 9;  // uniform -> s_load
          half2_t wt0 = as_h2(wt[0]), wt1 = as_h2(wt[1]), wt2 = as_h2(wt[2]),
                  wt3 = as_h2(wt[3]), wt4 = as_h2(wt[4]), wt5 = as_h2(wt[5]),
                  wt6 = as_h2(wt[6]), wt7 = as_h2(wt[7]), wt8 = as_h2(wt[8]);
          D9(a[o][0], 0, 0);
          D9(a[o][1], 0, 1);
          D9(a[o][2], 1, 0);
          D9(a[o][3], 1, 1);
        }
      }
      int dx = fx & 1;
#pragma unroll
      for (int o = 0; o < 4; ++o) {
        float m = fmaxf(fmaxf(a[o][0], a[o][1]), fmaxf(a[o][2], a[o][3]));
        float fv = fmaxf(m + b2q[o], 0.f);  // f[4qs+o][fy][fx]
#pragma unroll
        for (int ot = 0; ot < 4; ++ot)
          partial[ot] += fv * wp[ot * 64 + (qs * 4 + o) * 4 + dy * 2 + dx];
      }
    }
    // combine dx pair (l^1), then dy pair (l +- 28); leaders write slot.
#pragma unroll
    for (int ot = 0; ot < 4; ++ot) {
      partial[ot] += __shfl_xor(partial[ot], 1, 64);
      partial[ot] += __shfl(partial[ot], (l < 28) ? (l + 28) : (l - 28), 64);
    }
    if (l < 28 && (l & 1) == 0) {
      int p = pass * 14 + (fx >> 1);
      *(float4*)&pfq[(qs * 98 + p) * 4] =
          make_float4(partial[0], partial[1], partial[2], partial[3]);
    }
  }
  __syncthreads();

  // ---- P3a: pfl = bp + sum_q pfq (overlay on dead hs region) ----
  float* pfl = (float*)hsu;
  for (int t2 = tid; t2 < 392; t2 += 256) {
    int p = t2 >> 2, ot = t2 & 3;
    pfl[t2] = bp[ot] + pfq[(0 * 98 + p) * 4 + ot] + pfq[(1 * 98 + p) * 4 + ot] +
              pfq[(2 * 98 + p) * 4 + ot] + pfq[(3 * 98 + p) * 4 + ot];
  }
  __syncthreads();

  // ---- P3b: fc1 partial over pf slice [392s, 392s+392) ----
  {
    int j = tid >> 2, q4 = tid & 3;
    const float2* wrow = (const float2*)(w_fc1 + j * 784 + 392 * s + q4 * 98);
    const float2* pv = (const float2*)(pfl + q4 * 98);
    float acc = 0.f;
#pragma unroll 7
    for (int m = 0; m < 49; ++m) {
      float2 wv = wrow[m], fv = pv[m];
      acc += wv.x * fv.x + wv.y * fv.y;
    }
    acc += __shfl_down(acc, 2, 4);
    acc += __shfl_down(acc, 1, 4);
    if (q4 == 0) h1p[((long)b * 2 + s) * 64 + j] = acc;
  }
}

// ---------------- k_tail: combine partials + fc2 + log_softmax --------------
__global__ __launch_bounds__(64) void k_tail(const float* __restrict__ h1p,
                                             const float* __restrict__ b_fc1,
                                             const float* __restrict__ w_fc2,
                                             const float* __restrict__ b_fc2,
                                             float* __restrict__ out) {
  __shared__ float h1s[64];
  __shared__ float red[11];
  int b = blockIdx.x, j = threadIdx.x;
  float v = b_fc1[j] + h1p[(long)b * 128 + j] + h1p[(long)b * 128 + 64 + j];
  h1s[j] = fmaxf(v, 0.f);
  __syncthreads();
  if (j < 10) {
    float acc = b_fc2[j];
    const float* wo = w_fc2 + j * 64;
#pragma unroll
    for (int k = 0; k < 64; ++k) acc += h1s[k] * wo[k];
    red[j] = acc;
  }
  __syncthreads();
  if (j == 0) {
    float mx = red[0];
    for (int o = 1; o < 10; ++o) mx = fmaxf(mx, red[o]);
    float se = 0.f;
    for (int o = 0; o < 10; ++o) se += expf(red[o] - mx);
    red[10] = mx + logf(se);
  }
  __syncthreads();
  if (j < 10) out[b * 10 + j] = red[j] - red[10];
}

extern "C" void kernel_launch(void* const* d_in, const int* in_sizes, int n_in,
                              void* d_out, int out_size, void* d_ws, size_t ws_size,
                              hipStream_t stream) {
  const float* x = (const float*)d_in[0];
  const float* w1 = (const float*)d_in[1];
  const float* b1 = (const float*)d_in[2];
  const float* w2 = (const float*)d_in[3];
  const float* b2 = (const float*)d_in[4];
  const float* wp = (const float*)d_in[5];
  const float* bp = (const float*)d_in[6];
  const float* wf1 = (const float*)d_in[7];
  const float* bf1 = (const float*)d_in[8];
  const float* wf2 = (const float*)d_in[9];
  const float* bf2 = (const float*)d_in[10];

  float* h1p = (float*)d_ws;              // [512][2][64] fc1 partials = 256 KB
  unsigned* pwbuf = (unsigned*)(h1p + 131072);  // [576] packed conv2 weights

  k_prew<<<dim3(3), 256, 0, stream>>>(w2, pwbuf);
  k_fused<<<dim3(1024), 256, 0, stream>>>(x, w1, b1, pwbuf, b2, wp, bp, wf1, h1p);
  k_tail<<<dim3(512), 64, 0, stream>>>(h1p, bf1, wf2, bf2, (float*)d_out);
}

// Round 12
// 140.472 us; speedup vs baseline: 1.5280x; 1.0791x over previous
//
#include <hip/hip_runtime.h>

// Fused pipeline; conv2 via MFMA implicit-GEMM (one 16x16x32_f16 strip = one patch):
//   k_prew: repack w2 -> bw u32[16 oc][48] f16 ic-pairs, k-order (icp,tap,pair), 36..47 = 0
//   k_fused (grid 1024 = b*2+s, 256 thr, 5 blocks/CU):
//     P1 conv1+relu+pool (fp32) -> LDS h-tile f16 ic-pairs hsu[4][30][58]
//     P2 per wave, strips p = wave..97 step 4 (patch p = (py,px)):
//        A[m=lane&15][k]: m = fmem*4+pos -> pre-pool pixel (4py+2a+dy, 4px+2b+dx);
//        per-lane k-octet (quad) gathered as 12 ds_read_b32 (offsets precomputed).
//        B[n=lane&15][k] from bw. 3 MFMA (K=96, zero-padded past 72).
//        C: lane(oc=lane&15, fmem=quad) rows = pool window -> max+bias+relu = fv;
//        patch-linear fv*wpv[ot], 64-lane butterfly, lane0 writes pfl[p*4..] (+bp).
//     P3 fc1 partial over pfl -> h1p[b][s][64]
//   k_tail: h1 = relu(sum_s h1p + b_fc1); fc2; log_softmax -> out[512,10]

#define HSTR 58   // 56 cols + 2 halo cols (u32 units)
#define NROWS 30  // 28 tile h-rows + 2 halo

typedef _Float16 half2_t __attribute__((ext_vector_type(2)));
typedef _Float16 f16x8 __attribute__((ext_vector_type(8)));
typedef float f32x4 __attribute__((ext_vector_type(4)));

__device__ __forceinline__ unsigned pack_f16(float a, float b) {
  union { half2_t h; unsigned u; } z;
  z.h[0] = (_Float16)a;
  z.h[1] = (_Float16)b;
  return z.u;
}

__device__ __forceinline__ f16x8 as_f16x8(uint4 u) {
  union { uint4 u; f16x8 f; } z;
  z.u = u;
  return z.f;
}

// fp32 9-tap conv dot (P1)
#define C9W(W, J, K)                                                           \
  (W[J][K] * w0_ + W[J][K + 1] * w1_ + W[J][K + 2] * w2_ + W[J + 1][K] * w3_ + \
   W[J + 1][K + 1] * w4_ + W[J + 1][K + 2] * w5_ + W[J + 2][K] * w6_ +         \
   W[J + 2][K + 1] * w7_ + W[J + 2][K + 2] * w8_)

// ---------------- k_prew: repack conv2 weights for MFMA B-operand ----------
// bw[oc*48 + k32]: k32 = icp*9 + tap (u32 = f16 pair (ic 2icp, 2icp+1) at tap);
// k32 in [36,48) = 0 (K zero-pad to 96 f16).
__global__ __launch_bounds__(256) void k_prew(const float* __restrict__ w2,
                                              unsigned* __restrict__ bw) {
  int t = blockIdx.x * 256 + threadIdx.x;
  if (t < 768) {
    int oc = t / 48, k32 = t % 48;
    unsigned v = 0u;
    if (k32 < 36) {
      int icp = k32 / 9, tap = k32 - icp * 9;
      v = pack_f16(w2[(oc * 8 + 2 * icp) * 9 + tap],
                   w2[(oc * 8 + 2 * icp + 1) * 9 + tap]);
    }
    bw[t] = v;
  }
}

__global__ __launch_bounds__(256, 5) void k_fused(
    const float* __restrict__ x, const float* __restrict__ w1,
    const float* __restrict__ b1, const unsigned* __restrict__ bw,
    const float* __restrict__ b2, const float* __restrict__ wp,
    const float* __restrict__ bp, const float* __restrict__ w_fc1,
    float* __restrict__ h1p) {
  __shared__ __align__(16) unsigned hsu[4 * NROWS * HSTR];  // 27.2 KB
  __shared__ __align__(16) float pfl[392];                  // 1.6 KB
  const int tid = threadIdx.x;
  const int b = blockIdx.x >> 1;
  const int s = blockIdx.x & 1;
  const int l = tid & 63;
  const int wv = __builtin_amdgcn_readfirstlane(tid >> 6);  // wave id 0..3
  const float* xb = x + (long)b * 12544;

  for (int i = tid; i < 4 * NROWS * HSTR; i += 256) hsu[i] = 0u;
  __syncthreads();

  // ---- P1: conv1(1->8)+bias+relu+maxpool2 -> f16-packed LDS tile ----
  // tile row r 0..29 <-> global pooled-h row gr = 28s-1+r; halo stays 0.
  for (int task = tid; task < 1680; task += 256) {
    int r = task / 56, hc = task % 56;
    int gr = 28 * s - 1 + r;
    if ((unsigned)gr >= 56u) continue;
    float win[4][4];
    int iy0 = 2 * gr - 1, ix0 = 2 * hc - 1;
#pragma unroll
    for (int rr = 0; rr < 4; ++rr) {
      int iy = iy0 + rr;
      bool yok = (unsigned)iy < 112u;
#pragma unroll
      for (int qq = 0; qq < 4; ++qq) {
        int ix = ix0 + qq;
        win[rr][qq] = (yok && (unsigned)ix < 112u) ? xb[iy * 112 + ix] : 0.f;
      }
    }
    float hv[8];
#pragma unroll
    for (int c = 0; c < 8; ++c) {
      float w0_ = w1[c * 9 + 0], w1_ = w1[c * 9 + 1], w2_ = w1[c * 9 + 2],
            w3_ = w1[c * 9 + 3], w4_ = w1[c * 9 + 4], w5_ = w1[c * 9 + 5],
            w6_ = w1[c * 9 + 6], w7_ = w1[c * 9 + 7], w8_ = w1[c * 9 + 8];
      float s00 = C9W(win, 0, 0), s01 = C9W(win, 0, 1), s10 = C9W(win, 1, 0),
            s11 = C9W(win, 1, 1);
      float m = fmaxf(fmaxf(s00, s01), fmaxf(s10, s11));
      hv[c] = fmaxf(m + b1[c], 0.f);
    }
#pragma unroll
    for (int cp = 0; cp < 4; ++cp)
      hsu[(cp * NROWS + r) * HSTR + 1 + hc] = pack_f16(hv[2 * cp], hv[2 * cp + 1]);
  }
  __syncthreads();

  // ---- P2: conv2+pool+relu+patch-linear via MFMA, one strip = one patch ----
  {
    const int q = l >> 4;  // k-octet / fmem role
    // Per-lane A-gather offsets (u32 units), k32 = kk*16 + q*4 + i.
    int offs[12];
#pragma unroll
    for (int kk = 0; kk < 3; ++kk)
#pragma unroll
      for (int i = 0; i < 4; ++i) {
        int k32 = kk * 16 + q * 4 + i;
        int icp = k32 / 9, tap = k32 - icp * 9;
        int ty = tap / 3, tx = tap - ty * 3;
        offs[kk * 4 + i] = (icp * NROWS + ty) * HSTR + tx;  // junk if k32>=36 (unused)
      }
    // A-role pixel offsets: m = l&15 = fmem*4+pos, fmem=(a,b), pos=(dy,dx)
    const int yoff = 2 * ((l >> 3) & 1) + ((l >> 1) & 1);  // 2a+dy
    const int xoff = 2 * ((l >> 2) & 1) + (l & 1);         // 2b+dx
    // B-frags: lane n = l&15 = oc; u32s bw[n*48 + kk*16 + q*4 ..]
    uint4 bu0 = *(const uint4*)(bw + (l & 15) * 48 + 0 * 16 + q * 4);
    uint4 bu1 = *(const uint4*)(bw + (l & 15) * 48 + 1 * 16 + q * 4);
    uint4 bu2 = *(const uint4*)(bw + (l & 15) * 48 + 2 * 16 + q * 4);
    // C-role constants: lane = (oc = l&15, fmem = q)
    const float b2v = b2[l & 15];
    float wpv[4];
#pragma unroll
    for (int ot = 0; ot < 4; ++ot) wpv[ot] = wp[ot * 64 + (l & 15) * 4 + q];
    const float4 bpq = *(const float4*)bp;

#pragma unroll 1
    for (int p = wv; p < 98; p += 4) {
      int py = p / 14, px = p - py * 14;
      int base = (4 * py + yoff) * HSTR + 4 * px + xoff;
      uint4 a0u, a1u, a2u = make_uint4(0u, 0u, 0u, 0u);
      a0u.x = hsu[base + offs[0]];
      a0u.y = hsu[base + offs[1]];
      a0u.z = hsu[base + offs[2]];
      a0u.w = hsu[base + offs[3]];
      a1u.x = hsu[base + offs[4]];
      a1u.y = hsu[base + offs[5]];
      a1u.z = hsu[base + offs[6]];
      a1u.w = hsu[base + offs[7]];
      if (q == 0) {  // only k32 32..35 real in K-step 2
        a2u.x = hsu[base + offs[8]];
        a2u.y = hsu[base + offs[9]];
        a2u.z = hsu[base + offs[10]];
        a2u.w = hsu[base + offs[11]];
      }
      f32x4 acc = {0.f, 0.f, 0.f, 0.f};
      acc = __builtin_amdgcn_mfma_f32_16x16x32_f16(as_f16x8(a0u), as_f16x8(bu0), acc, 0, 0, 0);
      acc = __builtin_amdgcn_mfma_f32_16x16x32_f16(as_f16x8(a1u), as_f16x8(bu1), acc, 0, 0, 0);
      acc = __builtin_amdgcn_mfma_f32_16x16x32_f16(as_f16x8(a2u), as_f16x8(bu2), acc, 0, 0, 0);
      // lane holds D[m=4q+reg][oc]: 4 regs = pool window of f-pixel fmem=q
      float mx = fmaxf(fmaxf(acc[0], acc[1]), fmaxf(acc[2], acc[3]));
      float fv = fmaxf(mx + b2v, 0.f);
      float part0 = fv * wpv[0], part1 = fv * wpv[1], part2 = fv * wpv[2],
            part3 = fv * wpv[3];
#pragma unroll
      for (int d = 1; d < 64; d <<= 1) {
        part0 += __shfl_xor(part0, d, 64);
        part1 += __shfl_xor(part1, d, 64);
        part2 += __shfl_xor(part2, d, 64);
        part3 += __shfl_xor(part3, d, 64);
      }
      if (l == 0)
        *(float4*)&pfl[p * 4] = make_float4(part0 + bpq.x, part1 + bpq.y,
                                            part2 + bpq.z, part3 + bpq.w);
    }
  }
  __syncthreads();

  // ---- P3: fc1 partial over this tile's pf slice [392s, 392s+392) ----
  {
    int j = tid >> 2, q4 = tid & 3;
    const float2* wrow = (const float2*)(w_fc1 + j * 784 + 392 * s + q4 * 98);
    const float2* pv = (const float2*)(pfl + q4 * 98);
    float acc = 0.f;
#pragma unroll 7
    for (int m = 0; m < 49; ++m) {
      float2 wv2 = wrow[m], fv2 = pv[m];
      acc += wv2.x * fv2.x + wv2.y * fv2.y;
    }
    acc += __shfl_down(acc, 2, 4);
    acc += __shfl_down(acc, 1, 4);
    if (q4 == 0) h1p[((long)b * 2 + s) * 64 + j] = acc;
  }
}

// ---------------- k_tail: combine partials + fc2 + log_softmax --------------
__global__ __launch_bounds__(64) void k_tail(const float* __restrict__ h1p,
                                             const float* __restrict__ b_fc1,
                                             const float* __restrict__ w_fc2,
                                             const float* __restrict__ b_fc2,
                                             float* __restrict__ out) {
  __shared__ float h1s[64];
  __shared__ float red[11];
  int b = blockIdx.x, j = threadIdx.x;
  float v = b_fc1[j] + h1p[(long)b * 128 + j] + h1p[(long)b * 128 + 64 + j];
  h1s[j] = fmaxf(v, 0.f);
  __syncthreads();
  if (j < 10) {
    float acc = b_fc2[j];
    const float* wo = w_fc2 + j * 64;
#pragma unroll
    for (int k = 0; k < 64; ++k) acc += h1s[k] * wo[k];
    red[j] = acc;
  }
  __syncthreads();
  if (j == 0) {
    float mx = red[0];
    for (int o = 1; o < 10; ++o) mx = fmaxf(mx, red[o]);
    float se = 0.f;
    for (int o = 0; o < 10; ++o) se += expf(red[o] - mx);
    red[10] = mx + logf(se);
  }
  __syncthreads();
  if (j < 10) out[b * 10 + j] = red[j] - red[10];
}

extern "C" void kernel_launch(void* const* d_in, const int* in_sizes, int n_in,
                              void* d_out, int out_size, void* d_ws, size_t ws_size,
                              hipStream_t stream) {
  const float* x = (const float*)d_in[0];
  const float* w1 = (const float*)d_in[1];
  const float* b1 = (const float*)d_in[2];
  const float* w2 = (const float*)d_in[3];
  const float* b2 = (const float*)d_in[4];
  const float* wp = (const float*)d_in[5];
  const float* bp = (const float*)d_in[6];
  const float* wf1 = (const float*)d_in[7];
  const float* bf1 = (const float*)d_in[8];
  const float* wf2 = (const float*)d_in[9];
  const float* bf2 = (const float*)d_in[10];

  float* h1p = (float*)d_ws;                   // [512][2][64] = 65536 floats
  unsigned* bw = (unsigned*)(h1p + 65536);     // [768] packed MFMA B weights

  k_prew<<<dim3(3), 256, 0, stream>>>(w2, bw);
  k_fused<<<dim3(1024), 256, 0, stream>>>(x, w1, b1, bw, b2, wp, bp, wf1, h1p);
  k_tail<<<dim3(512), 64, 0, stream>>>(h1p, bf1, wf2, bf2, (float*)d_out);
}

// Round 13
// 126.347 us; speedup vs baseline: 1.6989x; 1.1118x over previous
//
#include <hip/hip_runtime.h>

// Fused pipeline; conv2 via MFMA implicit-GEMM; no per-strip butterfly:
//   k_prew: repack w2 -> bw u32[16 oc][48] f16 ic-pairs (k-order icp*9+tap, 36..47=0)
//   k_fused (grid 1024 = b*2+s, 256 thr, 4 blocks/CU):
//     P1 conv1+relu+pool via packed-f32 (v_pk_fma_f32) -> LDS f16 h-tile hsu[4][30][58]
//     P2 two chunks of 49 patches: per wave, strips p_l = wv..48 step 4:
//        A-frags gathered from hsu (12 ds_read_b32, precomputed offsets),
//        B-frags from bw; 3x mfma_f32_16x16x32_f16; lane (oc=l&15, fmem=l>>4)
//        -> max+bias+relu = fv -> ds_write_b16 fsu[p_l][l] (padded rows).
//        Chunk reduce: thread t<196: pfl[p*4+ot] = bp[ot] + 32x fdot2(fsu row, wpk).
//     P3 fc1 partial over pfl -> h1p[b][s][64]
//   k_tail: h1 = relu(sum_s h1p + b_fc1); fc2; log_softmax -> out[512,10]

#define HSTR 58   // 56 cols + 2 halo cols (u32 units)
#define NROWS 30  // 28 tile h-rows + 2 halo
#define FSTR 33   // fsu row stride in u32 (66 f16) -> conflict-free reduce

typedef _Float16 half2_t __attribute__((ext_vector_type(2)));
typedef _Float16 f16x8 __attribute__((ext_vector_type(8)));
typedef float f32x4 __attribute__((ext_vector_type(4)));
typedef float f32x2 __attribute__((ext_vector_type(2)));

__device__ __forceinline__ unsigned pack_f16(float a, float b) {
  union { half2_t h; unsigned u; } z;
  z.h[0] = (_Float16)a;
  z.h[1] = (_Float16)b;
  return z.u;
}

__device__ __forceinline__ half2_t as_h2(unsigned u) {
  union { unsigned u; half2_t h; } z;
  z.u = u;
  return z.h;
}

__device__ __forceinline__ f16x8 as_f16x8(uint4 u) {
  union { uint4 u; f16x8 f; } z;
  z.u = u;
  return z.f;
}

__device__ __forceinline__ float fdot2_(half2_t a, half2_t b, float c) {
#if __has_builtin(__builtin_amdgcn_fdot2)
  return __builtin_amdgcn_fdot2(a, b, c, false);
#else
  return c + (float)a[0] * (float)b[0] + (float)a[1] * (float)b[1];
#endif
}

// ---------------- k_prew: repack conv2 weights for MFMA B-operand ----------
__global__ __launch_bounds__(256) void k_prew(const float* __restrict__ w2,
                                              unsigned* __restrict__ bw) {
  int t = blockIdx.x * 256 + threadIdx.x;
  if (t < 768) {
    int oc = t / 48, k32 = t % 48;
    unsigned v = 0u;
    if (k32 < 36) {
      int icp = k32 / 9, tap = k32 - icp * 9;
      v = pack_f16(w2[(oc * 8 + 2 * icp) * 9 + tap],
                   w2[(oc * 8 + 2 * icp + 1) * 9 + tap]);
    }
    bw[t] = v;
  }
}

__global__ __launch_bounds__(256, 4) void k_fused(
    const float* __restrict__ x, const float* __restrict__ w1,
    const float* __restrict__ b1, const unsigned* __restrict__ bw,
    const float* __restrict__ b2, const float* __restrict__ wp,
    const float* __restrict__ bp, const float* __restrict__ w_fc1,
    float* __restrict__ h1p) {
  __shared__ __align__(16) unsigned hsu[4 * NROWS * HSTR];  // 27.2 KB
  __shared__ __align__(16) unsigned fsu[49 * FSTR];         // 6.3 KB (f16 rows)
  __shared__ __align__(16) float pfl[392];                  // 1.6 KB
  const int tid = threadIdx.x;
  const int b = blockIdx.x >> 1;
  const int s = blockIdx.x & 1;
  const int l = tid & 63;
  const int wv = __builtin_amdgcn_readfirstlane(tid >> 6);  // wave id 0..3
  const float* xb = x + (long)b * 12544;

  // Per-thread packed wp pairs for the chunk-reduce: this thread's ot = tid&3.
  // pair i covers lanes (2i, 2i+1); lane l -> wp[ot*64 + (l&15)*4 + (l>>4)].
  unsigned wpk[32];
  {
    int ot0 = tid & 3;
#pragma unroll
    for (int i = 0; i < 32; ++i) {
      int l0 = 2 * i, l1 = 2 * i + 1;
      wpk[i] = pack_f16(wp[ot0 * 64 + (l0 & 15) * 4 + (l0 >> 4)],
                        wp[ot0 * 64 + (l1 & 15) * 4 + (l1 >> 4)]);
    }
  }
  const float bpv = bp[tid & 3];

  for (int i = tid; i < 4 * NROWS * HSTR; i += 256) hsu[i] = 0u;
  __syncthreads();

  // ---- P1: conv1(1->8)+bias+relu+maxpool2 (packed f32) -> f16 LDS tile ----
  for (int task = tid; task < 1680; task += 256) {
    int r = task / 56, hc = task % 56;
    int gr = 28 * s - 1 + r;
    if ((unsigned)gr >= 56u) continue;
    float win[4][4];
    int iy0 = 2 * gr - 1, ix0 = 2 * hc - 1;
#pragma unroll
    for (int rr = 0; rr < 4; ++rr) {
      int iy = iy0 + rr;
      bool yok = (unsigned)iy < 112u;
#pragma unroll
      for (int qq = 0; qq < 4; ++qq) {
        int ix = ix0 + qq;
        win[rr][qq] = (yok && (unsigned)ix < 112u) ? xb[iy * 112 + ix] : 0.f;
      }
    }
    float hv[8];
#pragma unroll
    for (int c = 0; c < 8; ++c) {
      f32x2 sA = {0.f, 0.f};  // (s00, s01)
      f32x2 sB = {0.f, 0.f};  // (s10, s11)
#pragma unroll
      for (int ty = 0; ty < 3; ++ty)
#pragma unroll
        for (int tx = 0; tx < 3; ++tx) {
          float wk = w1[c * 9 + ty * 3 + tx];
          f32x2 wkk = {wk, wk};
          f32x2 xa = {win[ty][tx], win[ty][tx + 1]};
          f32x2 xb2 = {win[ty + 1][tx], win[ty + 1][tx + 1]};
          sA = __builtin_elementwise_fma(xa, wkk, sA);
          sB = __builtin_elementwise_fma(xb2, wkk, sB);
        }
      f32x2 sm = __builtin_elementwise_max(sA, sB);
      float m = fmaxf(sm.x, sm.y);
      hv[c] = fmaxf(m + b1[c], 0.f);
    }
#pragma unroll
    for (int cp = 0; cp < 4; ++cp)
      hsu[(cp * NROWS + r) * HSTR + 1 + hc] = pack_f16(hv[2 * cp], hv[2 * cp + 1]);
  }
  __syncthreads();

  // ---- P2: conv2+pool+relu via MFMA; fv -> fsu; chunked patch reduce ----
  {
    const int q = l >> 4;  // k-octet / fmem role
    int offs[12];
#pragma unroll
    for (int kk = 0; kk < 3; ++kk)
#pragma unroll
      for (int i = 0; i < 4; ++i) {
        int k32 = kk * 16 + q * 4 + i;
        int icp = k32 / 9, tap = k32 - icp * 9;
        int ty = tap / 3, tx = tap - ty * 3;
        offs[kk * 4 + i] = (icp * NROWS + ty) * HSTR + tx;  // junk if k32>=36
      }
    const int yoff = 2 * ((l >> 3) & 1) + ((l >> 1) & 1);  // 2a+dy
    const int xoff = 2 * ((l >> 2) & 1) + (l & 1);         // 2b+dx
    uint4 bu0 = *(const uint4*)(bw + (l & 15) * 48 + 0 * 16 + q * 4);
    uint4 bu1 = *(const uint4*)(bw + (l & 15) * 48 + 1 * 16 + q * 4);
    uint4 bu2 = *(const uint4*)(bw + (l & 15) * 48 + 2 * 16 + q * 4);
    const float b2v = b2[l & 15];
    _Float16* fsh = (_Float16*)fsu;

#pragma unroll 1
    for (int c = 0; c < 2; ++c) {  // chunk: patches c*49 .. c*49+48
#pragma unroll 1
      for (int p_l = wv; p_l < 49; p_l += 4) {
        int p = c * 49 + p_l;
        int py = p / 14, px = p - py * 14;
        int base = (4 * py + yoff) * HSTR + 4 * px + xoff;
        uint4 a0u, a1u, a2u = make_uint4(0u, 0u, 0u, 0u);
        a0u.x = hsu[base + offs[0]];
        a0u.y = hsu[base + offs[1]];
        a0u.z = hsu[base + offs[2]];
        a0u.w = hsu[base + offs[3]];
        a1u.x = hsu[base + offs[4]];
        a1u.y = hsu[base + offs[5]];
        a1u.z = hsu[base + offs[6]];
        a1u.w = hsu[base + offs[7]];
        if (q == 0) {  // only k32 32..35 real in K-step 2
          a2u.x = hsu[base + offs[8]];
          a2u.y = hsu[base + offs[9]];
          a2u.z = hsu[base + offs[10]];
          a2u.w = hsu[base + offs[11]];
        }
        f32x4 acc = {0.f, 0.f, 0.f, 0.f};
        acc = __builtin_amdgcn_mfma_f32_16x16x32_f16(as_f16x8(a0u), as_f16x8(bu0), acc, 0, 0, 0);
        acc = __builtin_amdgcn_mfma_f32_16x16x32_f16(as_f16x8(a1u), as_f16x8(bu1), acc, 0, 0, 0);
        acc = __builtin_amdgcn_mfma_f32_16x16x32_f16(as_f16x8(a2u), as_f16x8(bu2), acc, 0, 0, 0);
        float mx = fmaxf(fmaxf(acc[0], acc[1]), fmaxf(acc[2], acc[3]));
        float fv = fmaxf(mx + b2v, 0.f);  // f[oc=l&15][f-pixel fmem=q of patch p]
        fsh[p_l * (2 * FSTR) + l] = (_Float16)fv;
      }
      __syncthreads();
      // chunk reduce: thread t<196 -> (row=p_l, ot); 32 fdot2 over 64 lanes
      if (tid < 196) {
        int row = tid >> 2, ot = tid & 3;
        int p = c * 49 + row;
        const unsigned* fr = fsu + row * FSTR;
        float acc = 0.f;
#pragma unroll
        for (int i = 0; i < 32; ++i) acc = fdot2_(as_h2(fr[i]), as_h2(wpk[i]), acc);
        pfl[p * 4 + ot] = acc + bpv;
      }
      __syncthreads();
    }
  }

  // ---- P3: fc1 partial over this tile's pf slice [392s, 392s+392) ----
  {
    int j = tid >> 2, q4 = tid & 3;
    const float2* wrow = (const float2*)(w_fc1 + j * 784 + 392 * s + q4 * 98);
    const float2* pv = (const float2*)(pfl + q4 * 98);
    float acc = 0.f;
#pragma unroll 7
    for (int m = 0; m < 49; ++m) {
      float2 wv2 = wrow[m], fv2 = pv[m];
      acc += wv2.x * fv2.x + wv2.y * fv2.y;
    }
    acc += __shfl_down(acc, 2, 4);
    acc += __shfl_down(acc, 1, 4);
    if (q4 == 0) h1p[((long)b * 2 + s) * 64 + j] = acc;
  }
}

// ---------------- k_tail: combine partials + fc2 + log_softmax --------------
__global__ __launch_bounds__(64) void k_tail(const float* __restrict__ h1p,
                                             const float* __restrict__ b_fc1,
                                             const float* __restrict__ w_fc2,
                                             const float* __restrict__ b_fc2,
                                             float* __restrict__ out) {
  __shared__ float h1s[64];
  __shared__ float red[11];
  int b = blockIdx.x, j = threadIdx.x;
  float v = b_fc1[j] + h1p[(long)b * 128 + j] + h1p[(long)b * 128 + 64 + j];
  h1s[j] = fmaxf(v, 0.f);
  __syncthreads();
  if (j < 10) {
    float acc = b_fc2[j];
    const float* wo = w_fc2 + j * 64;
#pragma unroll
    for (int k = 0; k < 64; ++k) acc += h1s[k] * wo[k];
    red[j] = acc;
  }
  __syncthreads();
  if (j == 0) {
    float mx = red[0];
    for (int o = 1; o < 10; ++o) mx = fmaxf(mx, red[o]);
    float se = 0.f;
    for (int o = 0; o < 10; ++o) se += expf(red[o] - mx);
    red[10] = mx + logf(se);
  }
  __syncthreads();
  if (j < 10) out[b * 10 + j] = red[j] - red[10];
}

extern "C" void kernel_launch(void* const* d_in, const int* in_sizes, int n_in,
                              void* d_out, int out_size, void* d_ws, size_t ws_size,
                              hipStream_t stream) {
  const float* x = (const float*)d_in[0];
  const float* w1 = (const float*)d_in[1];
  const float* b1 = (const float*)d_in[2];
  const float* w2 = (const float*)d_in[3];
  const float* b2 = (const float*)d_in[4];
  const float* wp = (const float*)d_in[5];
  const float* bp = (const float*)d_in[6];
  const float* wf1 = (const float*)d_in[7];
  const float* bf1 = (const float*)d_in[8];
  const float* wf2 = (const float*)d_in[9];
  const float* bf2 = (const float*)d_in[10];

  float* h1p = (float*)d_ws;                // [512][2][64] = 65536 floats
  unsigned* bw = (unsigned*)(h1p + 65536);  // [768] packed MFMA B weights

  k_prew<<<dim3(3), 256, 0, stream>>>(w2, bw);
  k_fused<<<dim3(1024), 256, 0, stream>>>(x, w1, b1, bw, b2, wp, bp, wf1, h1p);
  k_tail<<<dim3(512), 64, 0, stream>>>(h1p, bf1, wf2, bf2, (float*)d_out);
}